// Round 10
// baseline (662.046 us; speedup 1.0000x reference)
//
#include <hip/hip_runtime.h>
#include <hip/hip_bf16.h>
#include <math.h>

#define DD 128
#define HEADS 8
#define HID 16
#define NEG_SLOPE 0.2f
#define N_LAYERS 5
#define N_GRAPHS 64
#define N_CLASSES 10
#define NBINS 256
#define BIN_CAP 8192

typedef __bf16 bf16x8 __attribute__((ext_vector_type(8)));
typedef float f32x4 __attribute__((ext_vector_type(4)));

__device__ __forceinline__ float bflo(unsigned u) { return __uint_as_float(u << 16); }
__device__ __forceinline__ float bfhi(unsigned u) { return __uint_as_float(u & 0xffff0000u); }
__device__ __forceinline__ float bf1(unsigned short us) { return __uint_as_float(((unsigned)us) << 16); }
// float -> bf16 (round-to-nearest-even), bit-twiddle; finite inputs only
__device__ __forceinline__ unsigned short f2bf(float f) {
    unsigned u = __float_as_uint(f);
    u += 0x7fffu + ((u >> 16) & 1u);
    return (unsigned short)(u >> 16);
}
__device__ __forceinline__ unsigned pack2bf(float a, float b) {
    return (unsigned)f2bf(a) | ((unsigned)f2bf(b) << 16);
}

#define WCNT (N_LAYERS * 4 * 16 * 64)   // wprep thread count (20480)

// device-scope grid barrier: all blocks co-resident (grid <= 256 blocks).
// cnt zeroed by hipMemsetAsync before launch.
__device__ __forceinline__ void gbar(int* cnt, int target) {
    __syncthreads();
    if (threadIdx.x == 0) {
        __threadfence();
        atomicAdd(cnt, 1);
        while (atomicAdd(cnt, 0) < target) { }
        __threadfence();
    }
    __syncthreads();
}

// ---------------- fused prep: setup + binned CSR build, one 256-block kernel ----
// phase0: x->bf16 convert | weight swizzle | zero pooled/counts | per-chunk bin histogram
// phase1: per-bin scan of 256 chunk counts   phase2: scan of bin totals (block 0)
// phase3: binned scatter (packed src|dst<<16) phase4: per-bin CSR build in LDS

__global__ __launch_bounds__(256) void k_prep(
        const float* __restrict__ x, unsigned* __restrict__ xb,
        const float* __restrict__ Wl, const float* __restrict__ Wr,
        unsigned short* __restrict__ wB, float* __restrict__ pooled,
        float* __restrict__ counts, const int* __restrict__ ei,
        int* __restrict__ cnt, int* __restrict__ btot, int* __restrict__ bin_start,
        unsigned* __restrict__ binned, int* __restrict__ csr_src, int* __restrict__ row_ptr,
        int* __restrict__ bar, int n2, int n_nodes, int n_edges, int n_total,
        int chunk, unsigned long long bin_mul) {
    __shared__ int smem[BIN_CAP];
    __shared__ int saux[256];
    __shared__ int swsum[4];
    int t = threadIdx.x, blk = blockIdx.x;
    int wv = t >> 6, ln = t & 63;

    // ---- phase 0a: grid-stride setup ----
    int setupTotal = n2 + WCNT + N_GRAPHS * DD + N_GRAPHS;
    for (int id = blk * 256 + t; id < setupTotal; id += 256 * 256) {
        int i = id;
        if (i < n2) {
            float2 v = *(const float2*)(x + 2 * (size_t)i);
            xb[i] = pack2bf(v.x, v.y);
            continue;
        }
        i -= n2;
        if (i < WCNT) {
            int lane = i & 63;
            int ntg  = (i >> 6) & 15;
            int ks   = (i >> 10) & 3;
            int l    = i >> 12;
            int q = lane >> 4, r = lane & 15;
            int n = ntg * 16 + r;
            const float* W = ((n < DD) ? Wl : Wr) + (size_t)l * DD * DD;
            int nn = n & (DD - 1);
            size_t off = (size_t)l * (4 * 16 * 64 * 8) + ((size_t)(ks * 16 + ntg) * 64 + lane) * 8;
            for (int j = 0; j < 8; ++j) {
                int k = ks * 32 + q * 8 + j;
                wB[off + j] = f2bf(W[(size_t)k * DD + nn]);
            }
            continue;
        }
        i -= WCNT;
        if (i < N_GRAPHS * DD) { pooled[i] = 0.f; continue; }
        i -= N_GRAPHS * DD;
        counts[i] = 0.f;
    }
    // ---- phase 0b: bin histogram for this block's edge chunk ----
    saux[t] = 0;
    __syncthreads();
    {
        int beg = blk * chunk;
        int end = beg + chunk; if (end > n_total) end = n_total;
        for (int e = beg + t; e < end; e += 256) {
            int d = (e < n_edges) ? ei[n_edges + e] : (e - n_edges);
            int b = (int)(((unsigned long long)(unsigned)d * bin_mul) >> 32);
            atomicAdd(&saux[b], 1);
        }
    }
    __syncthreads();
    cnt[t * 256 + blk] = saux[t];        // cnt[bin][chunk]
    gbar(bar, 256);

    // ---- phase 1: block b scans cnt[b][0..255] -> exclusive (in place), btot[b] ----
    {
        int v = cnt[blk * 256 + t];
        int xx = v;
#pragma unroll
        for (int ofs = 1; ofs < 64; ofs <<= 1) {
            int tt = __shfl_up(xx, ofs);
            if (ln >= ofs) xx += tt;
        }
        if (ln == 63) swsum[wv] = xx;
        __syncthreads();
        int off = 0;
        for (int k = 0; k < wv; k++) off += swsum[k];
        int incl = off + xx;
        cnt[blk * 256 + t] = incl - v;
        if (t == 255) btot[blk] = incl;
    }
    gbar(bar, 512);

    // ---- phase 2: block 0 scans bin totals -> bin_start[257], row_ptr[n]=total ----
    if (blk == 0) {
        int v = btot[t];
        int xx = v;
#pragma unroll
        for (int ofs = 1; ofs < 64; ofs <<= 1) {
            int tt = __shfl_up(xx, ofs);
            if (ln >= ofs) xx += tt;
        }
        if (ln == 63) swsum[wv] = xx;
        __syncthreads();
        int off = 0;
        for (int k = 0; k < wv; k++) off += swsum[k];
        int incl = off + xx;
        bin_start[t] = incl - v;
        if (t == 255) { bin_start[256] = incl; row_ptr[n_nodes] = incl; }
    }
    gbar(bar, 768);

    // ---- phase 3: binned scatter ----
    saux[t] = bin_start[t] + cnt[t * 256 + blk];
    __syncthreads();
    {
        int beg = blk * chunk;
        int end = beg + chunk; if (end > n_total) end = n_total;
        for (int e = beg + t; e < end; e += 256) {
            int s, d;
            if (e < n_edges) { s = ei[e]; d = ei[n_edges + e]; }
            else { s = d = e - n_edges; }
            int b = (int)(((unsigned long long)(unsigned)d * bin_mul) >> 32);
            int pos = atomicAdd(&saux[b], 1);
            binned[pos] = (unsigned)s | ((unsigned)d << 16);
        }
    }
    gbar(bar, 1024);

    // ---- phase 4: per-bin CSR build (block = bin) ----
    {
        int b = blk;
        int lo = (int)(((((unsigned long long)b) << 32) + bin_mul - 1) / bin_mul);
        int hi = (int)(((((unsigned long long)(b + 1)) << 32) + bin_mul - 1) / bin_mul);
        if (hi > n_nodes) hi = n_nodes;
        int estart = bin_start[b], eend = bin_start[b + 1];
        int ne = eend - estart;
        saux[t] = 0;
        __syncthreads();
        for (int k = t; k < ne; k += 256) {
            unsigned v = binned[estart + k];
            atomicAdd(&saux[(int)(v >> 16) - lo], 1);
        }
        __syncthreads();
        int vdeg = saux[t];
        int xx = vdeg;
#pragma unroll
        for (int ofs = 1; ofs < 64; ofs <<= 1) {
            int tt = __shfl_up(xx, ofs);
            if (ln >= ofs) xx += tt;
        }
        if (ln == 63) swsum[wv] = xx;
        __syncthreads();
        int off = 0;
        for (int k = 0; k < wv; k++) off += swsum[k];
        int excl = off + xx - vdeg;
        if (lo + t < hi) row_ptr[lo + t] = estart + excl;
        __syncthreads();
        saux[t] = excl;                  // cursor
        __syncthreads();
        for (int k = t; k < ne; k += 256) {
            unsigned v = binned[estart + k];
            int pos = atomicAdd(&saux[(int)(v >> 16) - lo], 1);
            smem[pos] = (int)(v & 0xffffu);
        }
        __syncthreads();
        for (int k = t; k < ne; k += 256)
            csr_src[estart + k] = smem[k];
    }
}

// ---------------- MFMA GEMM (pure bf16): [xl|xr] = in @ [Wl|Wr] + [bl|br] -------

__global__ __launch_bounds__(256) void k_gemm_mfma(
    const unsigned short* __restrict__ in, const unsigned short* __restrict__ wB,
    const float* __restrict__ bl, const float* __restrict__ br,
    unsigned short* __restrict__ xl, unsigned short* __restrict__ xr, int n_nodes) {
    int w = threadIdx.x >> 6;
    int lane = threadIdx.x & 63;
    int q = lane >> 4, r = lane & 15;
    int blk = blockIdx.x;

    f32x4 acc[4][4] = {};
#pragma unroll
    for (int ks = 0; ks < 4; ++ks) {
        bf16x8 bh[4];
#pragma unroll
        for (int nt = 0; nt < 4; ++nt) {
            int ntg = w * 4 + nt;
            bh[nt] = *(const bf16x8*)(wB + ((size_t)(ks * 16 + ntg) * 64 + lane) * 8);
        }
        bf16x8 ah[4];
#pragma unroll
        for (int mt = 0; mt < 4; ++mt) {
            int node = blk * 64 + mt * 16 + r;
            if (node >= n_nodes) node = n_nodes - 1;   // clamp; stores guarded
            ah[mt] = *(const bf16x8*)(in + (size_t)node * DD + ks * 32 + q * 8);
        }
#pragma unroll
        for (int mt = 0; mt < 4; ++mt)
#pragma unroll
            for (int nt = 0; nt < 4; ++nt)
                acc[mt][nt] = __builtin_amdgcn_mfma_f32_16x16x32_bf16(ah[mt], bh[nt], acc[mt][nt], 0, 0, 0);
    }
#pragma unroll
    for (int nt = 0; nt < 4; ++nt) {
        int col = w * 64 + nt * 16 + r;
        float bv = (col < DD) ? bl[col] : br[col - DD];
        unsigned short* dstbase = (col < DD) ? (xl + col) : (xr + (col - DD));
#pragma unroll
        for (int mt = 0; mt < 4; ++mt)
#pragma unroll
            for (int reg = 0; reg < 4; ++reg) {
                int node = blk * 64 + mt * 16 + q * 4 + reg;
                if (node < n_nodes)
                    dstbase[(size_t)node * DD] = f2bf(acc[mt][nt][reg] + bv);
            }
    }
}

// ---------------- per-node aggregation: plain-exp softmax, 4 edges/iter ----------

__global__ __launch_bounds__(256) void k_node_agg(
    const unsigned short* __restrict__ xl, const unsigned short* __restrict__ xr,
    const int* __restrict__ row_ptr, const int* __restrict__ csr_src,
    const float* __restrict__ att, const float* __restrict__ bias,
    unsigned short* __restrict__ h_out, int n_nodes) {
    int wave = threadIdx.x >> 6;
    int lane = threadIdx.x & 63;
    int node = blockIdx.x * 4 + wave;
    if (node >= n_nodes) return;
    int grp = lane >> 4, sl = lane & 15;
    int beg = row_ptr[node], end = row_ptr[node + 1];

    uint4 xru = *(const uint4*)(xr + (size_t)node * DD + sl * 8);
    float xr0 = bflo(xru.x), xr1 = bfhi(xru.x), xr2 = bflo(xru.y), xr3 = bfhi(xru.y);
    float xr4 = bflo(xru.z), xr5 = bfhi(xru.z), xr6 = bflo(xru.w), xr7 = bfhi(xru.w);
    float4 at0 = *(const float4*)(att + sl * 8);
    float4 at1 = *(const float4*)(att + sl * 8 + 4);

    float l = 0.f;
    float a0 = 0.f, a1 = 0.f, a2 = 0.f, a3 = 0.f, a4 = 0.f, a5 = 0.f, a6 = 0.f, a7 = 0.f;

    int t0 = beg + grp;
    uint4 xu = make_uint4(0u, 0u, 0u, 0u);
    int sidx = 0;
    if (t0 < end) {
        int s = csr_src[t0];
        xu = *(const uint4*)(xl + (size_t)s * DD + sl * 8);
    }
    if (t0 + 4 < end) sidx = csr_src[t0 + 4];

    for (int t = t0; t < end; t += 4) {
        uint4 cur = xu;
        int snew = 0;
        if (t + 8 < end) snew = csr_src[t + 8];
        if (t + 4 < end) xu = *(const uint4*)(xl + (size_t)sidx * DD + sl * 8);
        sidx = snew;

        float x0 = bflo(cur.x), x1 = bfhi(cur.x), x2 = bflo(cur.y), x3 = bfhi(cur.y);
        float x4 = bflo(cur.z), x5 = bfhi(cur.z), x6 = bflo(cur.w), x7 = bfhi(cur.w);
        float v0 = x0 + xr0; v0 = fmaxf(v0, NEG_SLOPE * v0);
        float v1 = x1 + xr1; v1 = fmaxf(v1, NEG_SLOPE * v1);
        float v2 = x2 + xr2; v2 = fmaxf(v2, NEG_SLOPE * v2);
        float v3 = x3 + xr3; v3 = fmaxf(v3, NEG_SLOPE * v3);
        float v4 = x4 + xr4; v4 = fmaxf(v4, NEG_SLOPE * v4);
        float v5 = x5 + xr5; v5 = fmaxf(v5, NEG_SLOPE * v5);
        float v6 = x6 + xr6; v6 = fmaxf(v6, NEG_SLOPE * v6);
        float v7 = x7 + xr7; v7 = fmaxf(v7, NEG_SLOPE * v7);
        float lg = at0.x * v0 + at0.y * v1 + at0.z * v2 + at0.w * v3 +
                   at1.x * v4 + at1.y * v5 + at1.z * v6 + at1.w * v7;
        lg += __shfl_xor(lg, 1);           // head logit (lanes 2h,2h+1)
        float p = __expf(lg);
        l += p;
        a0 += p * x0; a1 += p * x1; a2 += p * x2; a3 += p * x3;
        a4 += p * x4; a5 += p * x5; a6 += p * x6; a7 += p * x7;
    }
    // merge the 4 edge-groups (plain sums)
    l  += __shfl_xor(l, 16);  l  += __shfl_xor(l, 32);
    a0 += __shfl_xor(a0, 16); a0 += __shfl_xor(a0, 32);
    a1 += __shfl_xor(a1, 16); a1 += __shfl_xor(a1, 32);
    a2 += __shfl_xor(a2, 16); a2 += __shfl_xor(a2, 32);
    a3 += __shfl_xor(a3, 16); a3 += __shfl_xor(a3, 32);
    a4 += __shfl_xor(a4, 16); a4 += __shfl_xor(a4, 32);
    a5 += __shfl_xor(a5, 16); a5 += __shfl_xor(a5, 32);
    a6 += __shfl_xor(a6, 16); a6 += __shfl_xor(a6, 32);
    a7 += __shfl_xor(a7, 16); a7 += __shfl_xor(a7, 32);

    if (grp == 0) {
        float4 bv0 = *(const float4*)(bias + sl * 8);
        float4 bv1 = *(const float4*)(bias + sl * 8 + 4);
        float rl = 1.f / l;
        float o0 = a0 * rl + bv0.x; o0 = o0 > 0.f ? o0 : __expf(o0) - 1.f;
        float o1 = a1 * rl + bv0.y; o1 = o1 > 0.f ? o1 : __expf(o1) - 1.f;
        float o2 = a2 * rl + bv0.z; o2 = o2 > 0.f ? o2 : __expf(o2) - 1.f;
        float o3 = a3 * rl + bv0.w; o3 = o3 > 0.f ? o3 : __expf(o3) - 1.f;
        float o4 = a4 * rl + bv1.x; o4 = o4 > 0.f ? o4 : __expf(o4) - 1.f;
        float o5 = a5 * rl + bv1.y; o5 = o5 > 0.f ? o5 : __expf(o5) - 1.f;
        float o6 = a6 * rl + bv1.z; o6 = o6 > 0.f ? o6 : __expf(o6) - 1.f;
        float o7 = a7 * rl + bv1.w; o7 = o7 > 0.f ? o7 : __expf(o7) - 1.f;
        uint4 o;
        o.x = pack2bf(o0, o1); o.y = pack2bf(o2, o3);
        o.z = pack2bf(o4, o5); o.w = pack2bf(o6, o7);
        *(uint4*)(h_out + (size_t)node * DD + sl * 8) = o;
    }
}

// ---------------- fused pooling + head (256 blocks x 128 thr, one grid barrier) ----

__global__ __launch_bounds__(128) void k_pool_final(
        const unsigned short* __restrict__ h, const int* __restrict__ batch,
        float* __restrict__ pooled, float* __restrict__ counts,
        const float* __restrict__ Wout, const float* __restrict__ bout,
        float* __restrict__ out, int* __restrict__ bar, int n_nodes, int chunk) {
    int c = threadIdx.x;               // 0..127
    int beg = blockIdx.x * chunk;
    if (beg < n_nodes) {
        int end = beg + chunk; if (end > n_nodes) end = n_nodes;
        int cur = batch[beg];
        float acc = 0.f; int cnt = 0;
        for (int node = beg; node < end; ++node) {
            int g = batch[node];
            if (g != cur) {
                atomicAdd(&pooled[cur * DD + c], acc);
                if (c == 0) atomicAdd(&counts[cur], (float)cnt);
                acc = 0.f; cnt = 0; cur = g;
            }
            acc += bf1(h[(size_t)node * DD + c]);
            cnt++;
        }
        atomicAdd(&pooled[cur * DD + c], acc);
        if (c == 0) atomicAdd(&counts[cur], (float)cnt);
    }
    gbar(bar, 256);
    if (blockIdx.x == 0) {
        __shared__ float slog[N_GRAPHS * N_CLASSES];
        for (int i = c; i < N_GRAPHS * N_CLASSES; i += 128) {
            int g = i / N_CLASSES, cl = i % N_CLASSES;
            float cntv = fmaxf(counts[g], 1.f);
            float acc = bout[cl];
            for (int k = 0; k < DD; k++)
                acc += (pooled[g * DD + k] / cntv) * Wout[k * N_CLASSES + cl];
            slog[i] = acc;
        }
        __syncthreads();
        for (int g = c; g < N_GRAPHS; g += 128) {
            float mx = -INFINITY;
            for (int j = 0; j < N_CLASSES; j++) mx = fmaxf(mx, slog[g * N_CLASSES + j]);
            float se = 0.f;
            for (int j = 0; j < N_CLASSES; j++) se += __expf(slog[g * N_CLASSES + j] - mx);
            float lse = mx + __logf(se);
            for (int j = 0; j < N_CLASSES; j++)
                out[g * N_CLASSES + j] = slog[g * N_CLASSES + j] - lse;
        }
    }
}

extern "C" void kernel_launch(void* const* d_in, const int* in_sizes, int n_in,
                              void* d_out, int out_size, void* d_ws, size_t ws_size,
                              hipStream_t stream) {
    const float* x     = (const float*)d_in[0];
    const int*   ei    = (const int*)d_in[1];
    const int*   batch = (const int*)d_in[2];
    const float* Wl    = (const float*)d_in[3];
    const float* bl    = (const float*)d_in[4];
    const float* Wr    = (const float*)d_in[5];
    const float* br    = (const float*)d_in[6];
    const float* att   = (const float*)d_in[7];
    const float* bias  = (const float*)d_in[8];
    const float* Wout  = (const float*)d_in[9];
    const float* bout  = (const float*)d_in[10];
    float* out = (float*)d_out;

    int n_nodes = in_sizes[0] / DD;    // 50000
    int n_edges = in_sizes[1] / 2;     // 800000
    int n_total = n_edges + n_nodes;   // 850000 (with self loops)
    int ND = n_nodes * DD;             // 6.4M

    const int WPL = 4 * 16 * 64 * 8;   // 32768 bf16 per layer
    unsigned long long bin_mul = (((unsigned long long)NBINS) << 32) / (unsigned)n_nodes;

    // workspace: [256B barrier area] hb | xb | xlb | xrb (bf16) | wB | cnt | btot |
    //            bin_start | binned | csr_src | row_ptr | pooled | counts
    int* bar            = (int*)d_ws;             // bar[0]=prep, bar[1]=pool
    unsigned short* hb  = (unsigned short*)((char*)d_ws + 256);
    unsigned short* xb  = hb + (size_t)ND;
    unsigned short* xlb = xb + (size_t)ND;
    unsigned short* xrb = xlb + (size_t)ND;
    unsigned short* wB  = xrb + (size_t)ND;
    int*      cnt       = (int*)(wB + (size_t)N_LAYERS * WPL);
    int*      btot      = cnt + NBINS * 256;
    int*      bin_start = btot + NBINS;
    unsigned* binned    = (unsigned*)(bin_start + NBINS + 1);
    int*      csr_src   = (int*)(binned + n_total);
    int*      row_ptr   = csr_src + n_total;
    float*    pooled    = (float*)(row_ptr + n_nodes + 1);
    float*    counts    = pooled + N_GRAPHS * DD;

    dim3 b256(256);
    int gGemm = (n_nodes + 63) / 64;
    int gAgg  = (n_nodes + 3) / 4;
    int chunk = (n_total + 255) / 256;
    int poolChunk = (n_nodes + 255) / 256;
    int n2 = ND / 2;

    hipMemsetAsync(d_ws, 0, 256, stream);
    k_prep<<<256, b256, 0, stream>>>(x, (unsigned*)xb, Wl, Wr, wB, pooled, counts, ei,
                                     cnt, btot, bin_start, binned, csr_src, row_ptr,
                                     &bar[0], n2, n_nodes, n_edges, n_total, chunk, bin_mul);

    for (int l = 0; l < N_LAYERS; l++) {
        const float* bl_l   = bl   + (size_t)l * DD;
        const float* br_l   = br   + (size_t)l * DD;
        const float* att_l  = att  + (size_t)l * HEADS * HID;
        const float* bias_l = bias + (size_t)l * DD;
        const unsigned short* in = (l == 0) ? xb : hb;

        k_gemm_mfma<<<gGemm, b256, 0, stream>>>(in, wB + (size_t)l * WPL, bl_l, br_l,
                                                xlb, xrb, n_nodes);
        k_node_agg<<<gAgg, b256, 0, stream>>>(xlb, xrb, row_ptr, csr_src, att_l, bias_l, hb, n_nodes);
    }

    k_pool_final<<<256, dim3(128), 0, stream>>>(hb, batch, pooled, counts, Wout, bout,
                                                out, &bar[1], n_nodes, poolChunk);
}

// Round 11
// 500.970 us; speedup vs baseline: 1.3215x; 1.3215x over previous
//
#include <hip/hip_runtime.h>
#include <hip/hip_bf16.h>
#include <math.h>

#define DD 128
#define HEADS 8
#define HID 16
#define NEG_SLOPE 0.2f
#define N_LAYERS 5
#define N_GRAPHS 64
#define N_CLASSES 10
#define NBINS 256
#define BIN_CAP 8192

typedef __bf16 bf16x8 __attribute__((ext_vector_type(8)));
typedef float f32x4 __attribute__((ext_vector_type(4)));
typedef float f32x2 __attribute__((ext_vector_type(2)));

__device__ __forceinline__ float bflo(unsigned u) { return __uint_as_float(u << 16); }
__device__ __forceinline__ float bfhi(unsigned u) { return __uint_as_float(u & 0xffff0000u); }
__device__ __forceinline__ float bf1(unsigned short us) { return __uint_as_float(((unsigned)us) << 16); }
// float -> bf16 (round-to-nearest-even), bit-twiddle; finite inputs only
__device__ __forceinline__ unsigned short f2bf(float f) {
    unsigned u = __float_as_uint(f);
    u += 0x7fffu + ((u >> 16) & 1u);
    return (unsigned short)(u >> 16);
}
__device__ __forceinline__ unsigned pack2bf(float a, float b) {
    return (unsigned)f2bf(a) | ((unsigned)f2bf(b) << 16);
}
__device__ __forceinline__ f32x2 unpk(unsigned u) {
    f32x2 r; r.x = bflo(u); r.y = bfhi(u); return r;
}

#define WCNT (N_LAYERS * 4 * 16 * 64)   // wprep thread count (20480)

// ---------------- fused setup: convert x->bf16 | weight swizzle | zero pooled/counts ----

__global__ void k_setup(const float* __restrict__ x, unsigned* __restrict__ xb,
                        const float* __restrict__ Wl, const float* __restrict__ Wr,
                        unsigned short* __restrict__ wB,
                        float* __restrict__ pooled, float* __restrict__ counts, int n2) {
    int id = blockIdx.x * 256 + threadIdx.x;
    if (id < n2) {                                   // x -> bf16 (packed pairs)
        float2 v = *(const float2*)(x + 2 * (size_t)id);
        xb[id] = pack2bf(v.x, v.y);
        return;
    }
    id -= n2;
    if (id < WCNT) {                                 // weight swizzle
        int lane = id & 63;
        int ntg  = (id >> 6) & 15;
        int ks   = (id >> 10) & 3;
        int l    = id >> 12;
        int q = lane >> 4, r = lane & 15;
        int n = ntg * 16 + r;
        const float* W = ((n < DD) ? Wl : Wr) + (size_t)l * DD * DD;
        int nn = n & (DD - 1);
        size_t off = (size_t)l * (4 * 16 * 64 * 8) + ((size_t)(ks * 16 + ntg) * 64 + lane) * 8;
        for (int j = 0; j < 8; ++j) {
            int k = ks * 32 + q * 8 + j;
            wB[off + j] = f2bf(W[(size_t)k * DD + nn]);
        }
        return;
    }
    id -= WCNT;
    if (id < N_GRAPHS * DD) { pooled[id] = 0.f; return; }
    id -= N_GRAPHS * DD;
    if (id < N_GRAPHS) counts[id] = 0.f;
}

// ---------------- binned CSR build ----------------
// bin(d) = (d * bin_mul) >> 32 ; lo(b) = ceil(b*2^32 / bin_mul)

__global__ __launch_bounds__(256) void k_bin_cnt(const int* __restrict__ ei,
        int* __restrict__ cnt, int n_edges, int n_total, int chunk,
        unsigned long long bin_mul) {
    __shared__ int hist[NBINS];
    int tid = threadIdx.x;
    hist[tid] = 0;
    __syncthreads();
    int beg = blockIdx.x * chunk;
    int end = beg + chunk; if (end > n_total) end = n_total;
    for (int e = beg + tid; e < end; e += 256) {
        int d = (e < n_edges) ? ei[n_edges + e] : (e - n_edges);
        int b = (int)(((unsigned long long)(unsigned)d * bin_mul) >> 32);
        atomicAdd(&hist[b], 1);
    }
    __syncthreads();
    cnt[tid * 256 + blockIdx.x] = hist[tid];   // cnt[bin][blk]
}

__global__ __launch_bounds__(256) void k_bin_scan(int* __restrict__ cnt, int* __restrict__ btot) {
    __shared__ int wsum[4];
    int b = blockIdx.x, t = threadIdx.x, wv = t >> 6, ln = t & 63;
    int v = cnt[b * 256 + t];
    int x = v;
#pragma unroll
    for (int ofs = 1; ofs < 64; ofs <<= 1) {
        int tt = __shfl_up(x, ofs);
        if (ln >= ofs) x += tt;
    }
    if (ln == 63) wsum[wv] = x;
    __syncthreads();
    int off = 0;
    for (int k = 0; k < wv; k++) off += wsum[k];
    int incl = off + x;
    cnt[b * 256 + t] = incl - v;
    if (t == 255) btot[b] = incl;
}

__global__ __launch_bounds__(256) void k_tot_scan(const int* __restrict__ btot,
        int* __restrict__ bin_start, int* __restrict__ row_ptr, int n_nodes) {
    __shared__ int wsum[4];
    int t = threadIdx.x, wv = t >> 6, ln = t & 63;
    int v = btot[t];
    int x = v;
#pragma unroll
    for (int ofs = 1; ofs < 64; ofs <<= 1) {
        int tt = __shfl_up(x, ofs);
        if (ln >= ofs) x += tt;
    }
    if (ln == 63) wsum[wv] = x;
    __syncthreads();
    int off = 0;
    for (int k = 0; k < wv; k++) off += wsum[k];
    int incl = off + x;
    bin_start[t] = incl - v;
    if (t == 255) { bin_start[256] = incl; row_ptr[n_nodes] = incl; }
}

__global__ __launch_bounds__(256) void k_bin_scatter(const int* __restrict__ ei,
        const int* __restrict__ cnt, const int* __restrict__ bin_start,
        unsigned* __restrict__ binned, int n_edges, int n_total, int chunk,
        unsigned long long bin_mul) {
    __shared__ int cur[NBINS];
    int tid = threadIdx.x;
    cur[tid] = bin_start[tid] + cnt[tid * 256 + blockIdx.x];
    __syncthreads();
    int beg = blockIdx.x * chunk;
    int end = beg + chunk; if (end > n_total) end = n_total;
    for (int e = beg + tid; e < end; e += 256) {
        int s, d;
        if (e < n_edges) { s = ei[e]; d = ei[n_edges + e]; }
        else { s = d = e - n_edges; }
        int b = (int)(((unsigned long long)(unsigned)d * bin_mul) >> 32);
        int pos = atomicAdd(&cur[b], 1);
        binned[pos] = (unsigned)s | ((unsigned)d << 16);
    }
}

__global__ __launch_bounds__(256) void k_bin_csr(const unsigned* __restrict__ binned,
        const int* __restrict__ bin_start, int* __restrict__ csr_src,
        int* __restrict__ row_ptr, int n_nodes, unsigned long long bin_mul) {
    __shared__ int sbuf[BIN_CAP];
    __shared__ int ldeg[256];
    __shared__ int wsum[4];
    int b = blockIdx.x, t = threadIdx.x, wv = t >> 6, ln = t & 63;
    int lo = (int)(((((unsigned long long)b) << 32) + bin_mul - 1) / bin_mul);
    int hi = (int)(((((unsigned long long)(b + 1)) << 32) + bin_mul - 1) / bin_mul);
    if (hi > n_nodes) hi = n_nodes;
    int estart = bin_start[b], eend = bin_start[b + 1];
    int ne = eend - estart;
    ldeg[t] = 0;
    __syncthreads();
    for (int k = t; k < ne; k += 256) {
        unsigned v = binned[estart + k];
        atomicAdd(&ldeg[(int)(v >> 16) - lo], 1);
    }
    __syncthreads();
    int vdeg = ldeg[t];
    int x = vdeg;
#pragma unroll
    for (int ofs = 1; ofs < 64; ofs <<= 1) {
        int tt = __shfl_up(x, ofs);
        if (ln >= ofs) x += tt;
    }
    if (ln == 63) wsum[wv] = x;
    __syncthreads();
    int off = 0;
    for (int k = 0; k < wv; k++) off += wsum[k];
    int excl = off + x - vdeg;
    if (lo + t < hi) row_ptr[lo + t] = estart + excl;
    __syncthreads();
    ldeg[t] = excl;                      // reuse as cursor
    __syncthreads();
    for (int k = t; k < ne; k += 256) {
        unsigned v = binned[estart + k];
        int pos = atomicAdd(&ldeg[(int)(v >> 16) - lo], 1);
        sbuf[pos] = (int)(v & 0xffffu);
    }
    __syncthreads();
    for (int k = t; k < ne; k += 256)
        csr_src[estart + k] = sbuf[k];
}

// ---------------- MFMA GEMM (pure bf16): [xl|xr] = in @ [Wl|Wr] + [bl|br] -------

__global__ __launch_bounds__(256) void k_gemm_mfma(
    const unsigned short* __restrict__ in, const unsigned short* __restrict__ wB,
    const float* __restrict__ bl, const float* __restrict__ br,
    unsigned short* __restrict__ xl, unsigned short* __restrict__ xr, int n_nodes) {
    int w = threadIdx.x >> 6;
    int lane = threadIdx.x & 63;
    int q = lane >> 4, r = lane & 15;
    int blk = blockIdx.x;

    f32x4 acc[4][4] = {};
#pragma unroll
    for (int ks = 0; ks < 4; ++ks) {
        bf16x8 bh[4];
#pragma unroll
        for (int nt = 0; nt < 4; ++nt) {
            int ntg = w * 4 + nt;
            bh[nt] = *(const bf16x8*)(wB + ((size_t)(ks * 16 + ntg) * 64 + lane) * 8);
        }
        bf16x8 ah[4];
#pragma unroll
        for (int mt = 0; mt < 4; ++mt) {
            int node = blk * 64 + mt * 16 + r;
            if (node >= n_nodes) node = n_nodes - 1;   // clamp; stores guarded
            ah[mt] = *(const bf16x8*)(in + (size_t)node * DD + ks * 32 + q * 8);
        }
#pragma unroll
        for (int mt = 0; mt < 4; ++mt)
#pragma unroll
            for (int nt = 0; nt < 4; ++nt)
                acc[mt][nt] = __builtin_amdgcn_mfma_f32_16x16x32_bf16(ah[mt], bh[nt], acc[mt][nt], 0, 0, 0);
    }
#pragma unroll
    for (int nt = 0; nt < 4; ++nt) {
        int col = w * 64 + nt * 16 + r;
        float bv = (col < DD) ? bl[col] : br[col - DD];
        unsigned short* dstbase = (col < DD) ? (xl + col) : (xr + (col - DD));
#pragma unroll
        for (int mt = 0; mt < 4; ++mt)
#pragma unroll
            for (int reg = 0; reg < 4; ++reg) {
                int node = blk * 64 + mt * 16 + q * 4 + reg;
                if (node < n_nodes)
                    dstbase[(size_t)node * DD] = f2bf(acc[mt][nt][reg] + bv);
            }
    }
}

// ---------------- per-node aggregation: plain-exp softmax, 4 edges/iter, packed fp32 ----
// one wave per dst node; 16 lanes x 8 dims per edge (4 f32x2 pairs -> v_pk_* ops),
// 4 edge-groups in flight; head h = lanes {2h,2h+1} -> 1 shfl_xor per edge.
// leaky(v) = max(v, 0.2x + 0.2xr) with 0.2xr precomputed per node.

__global__ __launch_bounds__(256) void k_node_agg(
    const unsigned short* __restrict__ xl, const unsigned short* __restrict__ xr,
    const int* __restrict__ row_ptr, const int* __restrict__ csr_src,
    const float* __restrict__ att, const float* __restrict__ bias,
    unsigned short* __restrict__ h_out, int n_nodes) {
    int wave = threadIdx.x >> 6;
    int lane = threadIdx.x & 63;
    int node = blockIdx.x * 4 + wave;
    if (node >= n_nodes) return;
    int grp = lane >> 4, sl = lane & 15;
    int beg = row_ptr[node], end = row_ptr[node + 1];

    uint4 xru = *(const uint4*)(xr + (size_t)node * DD + sl * 8);
    f32x2 xr0 = unpk(xru.x), xr1 = unpk(xru.y), xr2 = unpk(xru.z), xr3 = unpk(xru.w);
    f32x2 xs0 = xr0 * NEG_SLOPE, xs1 = xr1 * NEG_SLOPE, xs2 = xr2 * NEG_SLOPE, xs3 = xr3 * NEG_SLOPE;
    float4 atA = *(const float4*)(att + sl * 8);
    float4 atB = *(const float4*)(att + sl * 8 + 4);
    f32x2 at0, at1, at2, at3;
    at0.x = atA.x; at0.y = atA.y; at1.x = atA.z; at1.y = atA.w;
    at2.x = atB.x; at2.y = atB.y; at3.x = atB.z; at3.y = atB.w;

    float l = 0.f;
    f32x2 A0 = {0.f, 0.f}, A1 = {0.f, 0.f}, A2 = {0.f, 0.f}, A3 = {0.f, 0.f};

    int t0 = beg + grp;
    uint4 xu = make_uint4(0u, 0u, 0u, 0u);
    int sidx = 0;
    if (t0 < end) {
        int s = csr_src[t0];
        xu = *(const uint4*)(xl + (size_t)s * DD + sl * 8);
    }
    if (t0 + 4 < end) sidx = csr_src[t0 + 4];

    for (int t = t0; t < end; t += 4) {
        uint4 cur = xu;
        int snew = 0;
        if (t + 8 < end) snew = csr_src[t + 8];
        if (t + 4 < end) xu = *(const uint4*)(xl + (size_t)sidx * DD + sl * 8);
        sidx = snew;

        f32x2 x0 = unpk(cur.x), x1 = unpk(cur.y), x2 = unpk(cur.z), x3 = unpk(cur.w);
        f32x2 v0 = x0 + xr0, v1 = x1 + xr1, v2 = x2 + xr2, v3 = x3 + xr3;
        f32x2 w0 = x0 * NEG_SLOPE + xs0, w1 = x1 * NEG_SLOPE + xs1;
        f32x2 w2 = x2 * NEG_SLOPE + xs2, w3 = x3 * NEG_SLOPE + xs3;
        f32x2 lv0 = __builtin_elementwise_max(v0, w0);
        f32x2 lv1 = __builtin_elementwise_max(v1, w1);
        f32x2 lv2 = __builtin_elementwise_max(v2, w2);
        f32x2 lv3 = __builtin_elementwise_max(v3, w3);
        f32x2 d = lv0 * at0;
        d = lv1 * at1 + d;
        d = lv2 * at2 + d;
        d = lv3 * at3 + d;
        float lg = d.x + d.y;
        lg += __shfl_xor(lg, 1);           // head logit (lanes 2h,2h+1)
        float p = __expf(lg);
        l += p;
        f32x2 p2; p2.x = p; p2.y = p;
        A0 = x0 * p2 + A0;
        A1 = x1 * p2 + A1;
        A2 = x2 * p2 + A2;
        A3 = x3 * p2 + A3;
    }
    // merge the 4 edge-groups (plain sums)
    l += __shfl_xor(l, 16); l += __shfl_xor(l, 32);
    A0.x += __shfl_xor(A0.x, 16); A0.x += __shfl_xor(A0.x, 32);
    A0.y += __shfl_xor(A0.y, 16); A0.y += __shfl_xor(A0.y, 32);
    A1.x += __shfl_xor(A1.x, 16); A1.x += __shfl_xor(A1.x, 32);
    A1.y += __shfl_xor(A1.y, 16); A1.y += __shfl_xor(A1.y, 32);
    A2.x += __shfl_xor(A2.x, 16); A2.x += __shfl_xor(A2.x, 32);
    A2.y += __shfl_xor(A2.y, 16); A2.y += __shfl_xor(A2.y, 32);
    A3.x += __shfl_xor(A3.x, 16); A3.x += __shfl_xor(A3.x, 32);
    A3.y += __shfl_xor(A3.y, 16); A3.y += __shfl_xor(A3.y, 32);

    if (grp == 0) {
        float4 bvA = *(const float4*)(bias + sl * 8);
        float4 bvB = *(const float4*)(bias + sl * 8 + 4);
        float rl = 1.f / l;
        float o0 = A0.x * rl + bvA.x; o0 = o0 > 0.f ? o0 : __expf(o0) - 1.f;
        float o1 = A0.y * rl + bvA.y; o1 = o1 > 0.f ? o1 : __expf(o1) - 1.f;
        float o2 = A1.x * rl + bvA.z; o2 = o2 > 0.f ? o2 : __expf(o2) - 1.f;
        float o3 = A1.y * rl + bvA.w; o3 = o3 > 0.f ? o3 : __expf(o3) - 1.f;
        float o4 = A2.x * rl + bvB.x; o4 = o4 > 0.f ? o4 : __expf(o4) - 1.f;
        float o5 = A2.y * rl + bvB.y; o5 = o5 > 0.f ? o5 : __expf(o5) - 1.f;
        float o6 = A3.x * rl + bvB.z; o6 = o6 > 0.f ? o6 : __expf(o6) - 1.f;
        float o7 = A3.y * rl + bvB.w; o7 = o7 > 0.f ? o7 : __expf(o7) - 1.f;
        uint4 o;
        o.x = pack2bf(o0, o1); o.y = pack2bf(o2, o3);
        o.z = pack2bf(o4, o5); o.w = pack2bf(o6, o7);
        *(uint4*)(h_out + (size_t)node * DD + sl * 8) = o;
    }
}

// ---------------- pooling + head ----------------

__global__ void k_pool2(const unsigned short* __restrict__ h, const int* __restrict__ batch,
                        float* __restrict__ pooled, float* __restrict__ counts,
                        int n_nodes, int chunk) {
    int c = threadIdx.x;               // 0..127
    int beg = blockIdx.x * chunk;
    if (beg >= n_nodes) return;
    int end = beg + chunk; if (end > n_nodes) end = n_nodes;
    int cur = batch[beg];
    float acc = 0.f; int cnt = 0;
    for (int node = beg; node < end; ++node) {
        int g = batch[node];
        if (g != cur) {
            atomicAdd(&pooled[cur * DD + c], acc);
            if (c == 0) atomicAdd(&counts[cur], (float)cnt);
            acc = 0.f; cnt = 0; cur = g;
        }
        acc += bf1(h[(size_t)node * DD + c]);
        cnt++;
    }
    atomicAdd(&pooled[cur * DD + c], acc);
    if (c == 0) atomicAdd(&counts[cur], (float)cnt);
}

__global__ void k_final(const float* __restrict__ pooled, const float* __restrict__ counts,
                        const float* __restrict__ Wout, const float* __restrict__ bout,
                        float* __restrict__ out) {
    __shared__ float slog[N_GRAPHS * N_CLASSES];
    int t = threadIdx.x;
    int g = t / N_CLASSES, c = t % N_CLASSES;
    float cnt = fmaxf(counts[g], 1.f);
    float acc = bout[c];
    for (int k = 0; k < DD; k++)
        acc += (pooled[g * DD + k] / cnt) * Wout[k * N_CLASSES + c];
    slog[t] = acc;
    __syncthreads();
    float mx = -INFINITY;
    for (int j = 0; j < N_CLASSES; j++) mx = fmaxf(mx, slog[g * N_CLASSES + j]);
    float se = 0.f;
    for (int j = 0; j < N_CLASSES; j++) se += __expf(slog[g * N_CLASSES + j] - mx);
    out[t] = acc - mx - __logf(se);
}

extern "C" void kernel_launch(void* const* d_in, const int* in_sizes, int n_in,
                              void* d_out, int out_size, void* d_ws, size_t ws_size,
                              hipStream_t stream) {
    const float* x     = (const float*)d_in[0];
    const int*   ei    = (const int*)d_in[1];
    const int*   batch = (const int*)d_in[2];
    const float* Wl    = (const float*)d_in[3];
    const float* bl    = (const float*)d_in[4];
    const float* Wr    = (const float*)d_in[5];
    const float* br    = (const float*)d_in[6];
    const float* att   = (const float*)d_in[7];
    const float* bias  = (const float*)d_in[8];
    const float* Wout  = (const float*)d_in[9];
    const float* bout  = (const float*)d_in[10];
    float* out = (float*)d_out;

    int n_nodes = in_sizes[0] / DD;    // 50000
    int n_edges = in_sizes[1] / 2;     // 800000
    int n_total = n_edges + n_nodes;   // 850000 (with self loops)
    int ND = n_nodes * DD;             // 6.4M

    const int WPL = 4 * 16 * 64 * 8;   // 32768 bf16 per layer
    unsigned long long bin_mul = (((unsigned long long)NBINS) << 32) / (unsigned)n_nodes;

    // workspace: hb | xb | xlb | xrb (bf16) | wB | cnt | btot | bin_start | binned |
    //            csr_src | row_ptr | pooled | counts
    unsigned short* hb  = (unsigned short*)d_ws;
    unsigned short* xb  = hb + (size_t)ND;
    unsigned short* xlb = xb + (size_t)ND;
    unsigned short* xrb = xlb + (size_t)ND;
    unsigned short* wB  = xrb + (size_t)ND;
    int*      cnt       = (int*)(wB + (size_t)N_LAYERS * WPL);
    int*      btot      = cnt + NBINS * 256;
    int*      bin_start = btot + NBINS;
    unsigned* binned    = (unsigned*)(bin_start + NBINS + 1);
    int*      csr_src   = (int*)(binned + n_total);
    int*      row_ptr   = csr_src + n_total;
    float*    pooled    = (float*)(row_ptr + n_nodes + 1);
    float*    counts    = pooled + N_GRAPHS * DD;

    dim3 b256(256);
    int gGemm = (n_nodes + 63) / 64;
    int gAgg  = (n_nodes + 3) / 4;
    int chunk = (n_total + 255) / 256;
    int poolBlocks = 1024;
    int poolChunk = (n_nodes + poolBlocks - 1) / poolBlocks;

    int n2 = ND / 2;
    int setupTotal = n2 + WCNT + N_GRAPHS * DD + N_GRAPHS;
    k_setup<<<(setupTotal + 255) / 256, b256, 0, stream>>>(x, (unsigned*)xb, Wl, Wr, wB,
                                                           pooled, counts, n2);
    k_bin_cnt<<<256, b256, 0, stream>>>(ei, cnt, n_edges, n_total, chunk, bin_mul);
    k_bin_scan<<<NBINS, b256, 0, stream>>>(cnt, btot);
    k_tot_scan<<<1, b256, 0, stream>>>(btot, bin_start, row_ptr, n_nodes);
    k_bin_scatter<<<256, b256, 0, stream>>>(ei, cnt, bin_start, binned, n_edges, n_total,
                                            chunk, bin_mul);
    k_bin_csr<<<NBINS, b256, 0, stream>>>(binned, bin_start, csr_src, row_ptr, n_nodes, bin_mul);

    for (int l = 0; l < N_LAYERS; l++) {
        const float* bl_l   = bl   + (size_t)l * DD;
        const float* br_l   = br   + (size_t)l * DD;
        const float* att_l  = att  + (size_t)l * HEADS * HID;
        const float* bias_l = bias + (size_t)l * DD;
        const unsigned short* in = (l == 0) ? xb : hb;

        k_gemm_mfma<<<gGemm, b256, 0, stream>>>(in, wB + (size_t)l * WPL, bl_l, br_l,
                                                xlb, xrb, n_nodes);
        k_node_agg<<<gAgg, b256, 0, stream>>>(xlb, xrb, row_ptr, csr_src, att_l, bias_l, hb, n_nodes);
    }

    k_pool2<<<poolBlocks, dim3(128), 0, stream>>>(hb, batch, pooled, counts, n_nodes, poolChunk);
    k_final<<<1, dim3(N_GRAPHS * N_CLASSES), 0, stream>>>(pooled, counts, Wout, bout, out);
}